// Round 4
// baseline (468.685 us; speedup 1.0000x reference)
//
#include <hip/hip_runtime.h>
#include <hip/hip_fp16.h>

// ComplexWindowAttn: B=2048 windows, DIM=96, HEADS=6, HEAD_DIM=16, N=64 (8x8).
// R11: drop xtr LDS staging (x is L2/L3-resident; qkv B-frags loaded straight
//      from global with identical f32->f16 rounding). LDS 66.5 -> 39.9 KB,
//      __launch_bounds__(512,6) -> 3 blocks/CU (24 waves) with no spill-cap.
//   - qkv unit remap: wave w owns B-tile nt=w&3 (loads x once/round),
//     ml = (w>>2)*3 + ui covers {Q,K,V}x{h0,h1}; coverage 6x4 unchanged.
//   - mg16 recomputed (not stored) to cut peak VGPR pressure.
//   - scores/softmax/bpermute-PV/proj phases: R10-verified code verbatim.
// Fallback: verified R6 fused scalar kernel if ws too small.

#define HEADS 6
#define BLOCK 512
#define SCALE 0.25f

typedef _Float16 f16x8 __attribute__((ext_vector_type(8)));
typedef float    f32x4 __attribute__((ext_vector_type(4)));

#define WQ_ELEMS   27648              // 288*96 per plane
#define WS_WQ_B    165888             // 3 planes * 27648 * 2B
#define WS_WP_B    36864              // 96*192 f16
#define WS_REL_B   98304              // 6*64*64 f32
#define WS_WP_OFF  WS_WQ_B
#define WS_REL_OFF (WS_WQ_B + WS_WP_B)
#define WS_NEED    (WS_WQ_B + WS_WP_B + WS_REL_B)

// ===================== K1: weight/bias preparation =====================
__global__ void prep_kernel(const float* __restrict__ wr,
                            const float* __restrict__ wi,
                            const float* __restrict__ pwr,
                            const float* __restrict__ pwi,
                            const float* __restrict__ rel,
                            __half* __restrict__ wq,
                            __half* __restrict__ wp,
                            float* __restrict__ rel_exp)
{
    int i = blockIdx.x * 256 + threadIdx.x;
    if (i < WQ_ELEMS) {
        wq[i]                 = __float2half(wr[i]);
        wq[WQ_ELEMS + i]      = __float2half(wi[i]);
        wq[2 * WQ_ELEMS + i]  = __float2half(-wi[i]);
    }
    if (i < 9216) {                       // 96*96 proj weights -> packed
        int o = i / 96, c = i - o * 96;
        int h = c >> 4, d = c & 15;
        wp[o * 192 + h * 32 + d]      = __float2half(pwr[i]);
        wp[o * 192 + h * 32 + 16 + d] = __float2half(-pwi[i]);
    }
    if (i < 24576) {                      // rel -> TRANSPOSED [h][m][n]
        int h = i >> 12, m = (i >> 6) & 63, n = i & 63;
        int idx = ((n >> 3) - (m >> 3) + 7) * 15 + ((n & 7) - (m & 7) + 7);
        rel_exp[i] = rel[h * 225 + idx];
    }
}

// ===================== fused kernel =====================
// LDS map (f16 units), total 19968 f16 = 39936 B -> 3 blocks/CU (LDS-wise 4):
//   sQ  [2][64][40] @ 0      (5120)   per-round, re@d im@16+d, *SCALE
//   sK  [2][64][40] @ 5120   (5120)
//   sVr [2][16][72] @ 10240  (2304)   [d][m]
//   sVi [2][16][72] @ 12544  (2304)
//   sO  [2][64][40] @ 14848  (5120)   Or@d, Oi@16+d
__global__ __launch_bounds__(BLOCK, 6) void fused_kernel(
    const float* __restrict__ x_real, const float* __restrict__ x_imag,
    const __half* __restrict__ wq,
    const __half* __restrict__ wp,
    const float* __restrict__ relT,
    float* __restrict__ out)
{
    __shared__ __align__(16) _Float16 smem[19968];

    _Float16* const sQ    = smem;
    _Float16* const sK    = smem + 5120;
    _Float16* const sVr   = smem + 10240;
    _Float16* const sVi   = smem + 12544;
    _Float16* const sO    = smem + 14848;

    const int b    = blockIdx.x;
    const int t    = threadIdx.x;
    const int lane = t & 63;
    const int w    = __builtin_amdgcn_readfirstlane(t >> 6);
    const int l16  = lane & 15;
    const int quad = lane >> 4;

    const float* xr = x_real + (size_t)b * 6144;   // [c][n]
    const float* xi = x_imag + (size_t)b * 6144;

    f32x4 pacc0 = {0.f,0.f,0.f,0.f};
    f32x4 pacc1 = {0.f,0.f,0.f,0.f};
    f32x4 pacc2 = {0.f,0.f,0.f,0.f};

    const _Float16* wpf = reinterpret_cast<const _Float16*>(wp);
    const __half* wr_p  = wq;
    const __half* wi_p  = wq + WQ_ELEMS;
    const __half* wni_p = wq + 2 * WQ_ELEMS;

    const int hr = w >> 2;          // head-in-round for attn (0/1)
    const int nb = w & 3;           // 16-col n-block for attn

    for (int ro = 0; ro < 3; ++ro) {
        // ---------- qkv cGEMM for heads 2ro, 2ro+1 ----------
        {
            // B-frags for this wave's tile (nt = w&3), loaded once from global
            const int n0 = (w & 3) * 16;
            f16x8 b_r[3], b_i[3];
#pragma unroll
            for (int ks = 0; ks < 3; ++ks) {
                const float* xrp = xr + (ks * 32 + quad * 8) * 64 + n0 + l16;
                const float* xip = xi + (ks * 32 + quad * 8) * 64 + n0 + l16;
                f16x8 vr, vi;
#pragma unroll
                for (int j = 0; j < 8; ++j) {
                    vr[j] = (_Float16)xrp[j * 64];
                    vi[j] = (_Float16)xip[j * 64];
                }
                b_r[ks] = vr;
                b_i[ks] = vi;
            }
#pragma unroll
            for (int ui = 0; ui < 3; ++ui) {
                const int ml  = (w >> 2) * 3 + ui;   // 0..5
                const int hl  = ml & 1;              // head-local
                const int mat = ml >> 1;             // 0=Q,1=K,2=V
                const int tile = mat * 6 + ro * 2 + hl;
                f16x8 a_r[3], a_i[3], a_ni[3];
#pragma unroll
                for (int ks = 0; ks < 3; ++ks) {
                    size_t off = (size_t)(tile * 16 + l16) * 96 + ks * 32 + quad * 8;
                    a_r[ks]  = *reinterpret_cast<const f16x8*>(wr_p  + off);
                    a_i[ks]  = *reinterpret_cast<const f16x8*>(wi_p  + off);
                    a_ni[ks] = *reinterpret_cast<const f16x8*>(wni_p + off);
                }
                f32x4 accr = {0.f, 0.f, 0.f, 0.f};
                f32x4 acci = {0.f, 0.f, 0.f, 0.f};
#pragma unroll
                for (int ks = 0; ks < 3; ++ks) {
                    accr = __builtin_amdgcn_mfma_f32_16x16x32_f16(a_r[ks],  b_r[ks], accr, 0, 0, 0);
                    accr = __builtin_amdgcn_mfma_f32_16x16x32_f16(a_ni[ks], b_i[ks], accr, 0, 0, 0);
                    acci = __builtin_amdgcn_mfma_f32_16x16x32_f16(a_r[ks],  b_i[ks], acci, 0, 0, 0);
                    acci = __builtin_amdgcn_mfma_f32_16x16x32_f16(a_i[ks],  b_r[ks], acci, 0, 0, 0);
                }
                // C: col n = n0+l16, row d = quad*4 + r (verified layout)
                const int n = n0 + l16;
                if (mat == 0) {                 // Q, pre-scaled
                    _Float16* q = sQ + hl * 2560 + n * 40;
#pragma unroll
                    for (int r = 0; r < 4; ++r) {
                        q[quad * 4 + r]      = (_Float16)(accr[r] * SCALE);
                        q[16 + quad * 4 + r] = (_Float16)(acci[r] * SCALE);
                    }
                } else if (mat == 1) {          // K
                    _Float16* kk = sK + hl * 2560 + n * 40;
#pragma unroll
                    for (int r = 0; r < 4; ++r) {
                        kk[quad * 4 + r]      = (_Float16)accr[r];
                        kk[16 + quad * 4 + r] = (_Float16)acci[r];
                    }
                } else {                        // V -> [d][m]
#pragma unroll
                    for (int r = 0; r < 4; ++r) {
                        sVr[hl * 1152 + (quad * 4 + r) * 72 + n] = (_Float16)accr[r];
                        sVi[hl * 1152 + (quad * 4 + r) * 72 + n] = (_Float16)acci[r];
                    }
                }
            }
        }
        __syncthreads();                        // B1

        const int hl = hr;
        const int hh = ro * 2 + hr;

        // ---------- swapped scores: C[m][n], lane owns n = nb*16+l16 ----------
        float sr16[4][4], si16[4][4];
        float mx = -1e30f;
        {
            const _Float16* qrow = sQ + hl * 2560 + (nb * 16 + l16) * 40;
            f16x8 bq  = *reinterpret_cast<const f16x8*>(qrow + quad * 8);
            f16x8 bq2 = *reinterpret_cast<const f16x8*>(qrow + ((quad + 2) & 3) * 8);
            if (quad >= 2) bq2 = -bq2;          // [Qi | -Qr]
#pragma unroll
            for (int tm = 0; tm < 4; ++tm) {
                f16x8 ak = *reinterpret_cast<const f16x8*>(
                    sK + hl * 2560 + (tm * 16 + l16) * 40 + quad * 8);
                f32x4 fr = {0.f,0.f,0.f,0.f}, fi = {0.f,0.f,0.f,0.f};
                fr = __builtin_amdgcn_mfma_f32_16x16x32_f16(ak, bq,  fr, 0, 0, 0);
                fi = __builtin_amdgcn_mfma_f32_16x16x32_f16(ak, bq2, fi, 0, 0, 0);
#pragma unroll
                for (int r = 0; r < 4; ++r) {
                    const int m = tm * 16 + quad * 4 + r;
                    float bb  = relT[hh * 4096 + m * 64 + nb * 16 + l16];
                    float vr_ = fr[r] + bb;
                    float vi_ = fi[r];
                    sr16[tm][r] = vr_; si16[tm][r] = vi_;
                    float m2  = fmaf(vr_, vr_, vi_ * vi_);
                    float rs  = __frsqrt_rn(m2 + 1e-16f);
                    mx = fmaxf(mx, m2 * rs);
                }
            }
        }
        mx = fmaxf(mx, __shfl_xor(mx, 16));
        mx = fmaxf(mx, __shfl_xor(mx, 32));
        float ss = 0.f;
#pragma unroll
        for (int tm = 0; tm < 4; ++tm)
#pragma unroll
            for (int r = 0; r < 4; ++r) {
                float vr_ = sr16[tm][r], vi_ = si16[tm][r];
                float m2  = fmaf(vr_, vr_, vi_ * vi_);
                float rs  = __frsqrt_rn(m2 + 1e-16f);
                ss += __expf(m2 * rs - mx);
            }
        ss += __shfl_xor(ss, 16);
        ss += __shfl_xor(ss, 32);
        const float inv = 1.0f / ss;

        // ---------- pack P[tm] (4 f16 per plane) ----------
        uint2 Pr[4], Pi[4];
#pragma unroll
        for (int tm = 0; tm < 4; ++tm) {
            float f_[4];
#pragma unroll
            for (int r = 0; r < 4; ++r) {
                float vr_ = sr16[tm][r], vi_ = si16[tm][r];
                float m2  = fmaf(vr_, vr_, vi_ * vi_);
                float rs  = __frsqrt_rn(m2 + 1e-16f);
                float mag = m2 * rs;
                float rs2 = __frsqrt_rn(fmaf(mag, mag, 1e-16f));
                f_[r] = __expf(mag - mx) * inv * rs2;
            }
            __half2 r01 = __floats2half2_rn(sr16[tm][0]*f_[0], sr16[tm][1]*f_[1]);
            __half2 r23 = __floats2half2_rn(sr16[tm][2]*f_[2], sr16[tm][3]*f_[3]);
            __half2 i01 = __floats2half2_rn(si16[tm][0]*f_[0], si16[tm][1]*f_[1]);
            __half2 i23 = __floats2half2_rn(si16[tm][2]*f_[2], si16[tm][3]*f_[3]);
            Pr[tm].x = *reinterpret_cast<unsigned*>(&r01);
            Pr[tm].y = *reinterpret_cast<unsigned*>(&r23);
            Pi[tm].x = *reinterpret_cast<unsigned*>(&i01);
            Pi[tm].y = *reinterpret_cast<unsigned*>(&i23);
        }

        // ---------- exchange -> PV A-frags, then PV MFMA ----------
        {
            const int srcA = (l16 + ((quad & 1) << 5)) << 2;
            const int srcB = srcA + 64;
            const bool hiq = (quad >= 2);
            union FU { unsigned u[4]; f16x8 v; };
            f32x4 oar = {0.f,0.f,0.f,0.f}, oai = {0.f,0.f,0.f,0.f};
#pragma unroll
            for (int ks = 0; ks < 2; ++ks) {
                FU fr_, fi_;
                {
                    unsigned a0 = __builtin_amdgcn_ds_bpermute(srcA, (int)Pr[2*ks].x);
                    unsigned a1 = __builtin_amdgcn_ds_bpermute(srcA, (int)Pr[2*ks].y);
                    unsigned a2 = __builtin_amdgcn_ds_bpermute(srcA, (int)Pr[2*ks+1].x);
                    unsigned a3 = __builtin_amdgcn_ds_bpermute(srcA, (int)Pr[2*ks+1].y);
                    unsigned b0 = __builtin_amdgcn_ds_bpermute(srcB, (int)Pr[2*ks].x);
                    unsigned b1 = __builtin_amdgcn_ds_bpermute(srcB, (int)Pr[2*ks].y);
                    unsigned b2 = __builtin_amdgcn_ds_bpermute(srcB, (int)Pr[2*ks+1].x);
                    unsigned b3 = __builtin_amdgcn_ds_bpermute(srcB, (int)Pr[2*ks+1].y);
                    fr_.u[0] = hiq ? a2 : a0;  fr_.u[1] = hiq ? a3 : a1;
                    fr_.u[2] = hiq ? b2 : b0;  fr_.u[3] = hiq ? b3 : b1;
                }
                {
                    unsigned a0 = __builtin_amdgcn_ds_bpermute(srcA, (int)Pi[2*ks].x);
                    unsigned a1 = __builtin_amdgcn_ds_bpermute(srcA, (int)Pi[2*ks].y);
                    unsigned a2 = __builtin_amdgcn_ds_bpermute(srcA, (int)Pi[2*ks+1].x);
                    unsigned a3 = __builtin_amdgcn_ds_bpermute(srcA, (int)Pi[2*ks+1].y);
                    unsigned b0 = __builtin_amdgcn_ds_bpermute(srcB, (int)Pi[2*ks].x);
                    unsigned b1 = __builtin_amdgcn_ds_bpermute(srcB, (int)Pi[2*ks].y);
                    unsigned b2 = __builtin_amdgcn_ds_bpermute(srcB, (int)Pi[2*ks+1].x);
                    unsigned b3 = __builtin_amdgcn_ds_bpermute(srcB, (int)Pi[2*ks+1].y);
                    fi_.u[0] = hiq ? a2 : a0;  fi_.u[1] = hiq ? a3 : a1;
                    fi_.u[2] = hiq ? b2 : b0;  fi_.u[3] = hiq ? b3 : b1;
                }
                const int ko = ks * 32 + quad * 8;
                f16x8 vr_ = *reinterpret_cast<const f16x8*>(&sVr[hl * 1152 + l16 * 72 + ko]);
                f16x8 vi_ = *reinterpret_cast<const f16x8*>(&sVi[hl * 1152 + l16 * 72 + ko]);
                oar = __builtin_amdgcn_mfma_f32_16x16x32_f16(fr_.v,  vr_,  oar, 0, 0, 0);
                oar = __builtin_amdgcn_mfma_f32_16x16x32_f16(fi_.v, -vi_,  oar, 0, 0, 0);
                oai = __builtin_amdgcn_mfma_f32_16x16x32_f16(fr_.v,  vi_,  oai, 0, 0, 0);
                oai = __builtin_amdgcn_mfma_f32_16x16x32_f16(fi_.v,  vr_,  oai, 0, 0, 0);
            }
#pragma unroll
            for (int r = 0; r < 4; ++r) {
                const int n = nb * 16 + quad * 4 + r;
                sO[hl * 2560 + n * 40 + l16]      = (_Float16)oar[r];
                sO[hl * 2560 + n * 40 + 16 + l16] = (_Float16)oai[r];
            }
        }
        __syncthreads();                        // B2

        // ---------- proj accumulate (R9-verified math) ----------
        {
            const int ob0 = (w & 1) * 3;
            const int pnb = w >> 1;
#pragma unroll
            for (int h2 = 0; h2 < 2; ++h2) {
                const _Float16* wb = wpf + (ro * 2 + h2) * 32 + quad * 8;
                f16x8 wb0 = *reinterpret_cast<const f16x8*>(wb + ((ob0    ) * 16 + l16) * 192);
                f16x8 wb1 = *reinterpret_cast<const f16x8*>(wb + ((ob0 + 1) * 16 + l16) * 192);
                f16x8 wb2 = *reinterpret_cast<const f16x8*>(wb + ((ob0 + 2) * 16 + l16) * 192);
                f16x8 a = *reinterpret_cast<const f16x8*>(
                    &sO[h2 * 2560 + (pnb * 16 + l16) * 40 + quad * 8]);
                pacc0 = __builtin_amdgcn_mfma_f32_16x16x32_f16(a, wb0, pacc0, 0, 0, 0);
                pacc1 = __builtin_amdgcn_mfma_f32_16x16x32_f16(a, wb1, pacc1, 0, 0, 0);
                pacc2 = __builtin_amdgcn_mfma_f32_16x16x32_f16(a, wb2, pacc2, 0, 0, 0);
            }
        }
        // next round's qkv writes (sQ/sK/sV) are disjoint from sO reads here;
        // B1 of the next round orders proj reads before the next sO writes.
    }

    // ---------- epilogue: out[o][n], o = (w&1)*48 + j*16 + l16 ----------
    {
        float* op = out + (size_t)b * 6144 + ((w & 1) * 48 + l16) * 64
                  + (w >> 1) * 16 + quad * 4;
        *reinterpret_cast<f32x4*>(op)        = pacc0;
        *reinterpret_cast<f32x4*>(op + 1024) = pacc1;
        *reinterpret_cast<f32x4*>(op + 2048) = pacc2;
    }
}

// ===================== Fallback: verified R6 fused kernel =====================
__global__ __launch_bounds__(BLOCK) void cwattn_kernel(
    const float* __restrict__ x_real, const float* __restrict__ x_imag,
    const float* __restrict__ qkv_wr, const float* __restrict__ qkv_wi,
    const float* __restrict__ proj_wr, const float* __restrict__ proj_wi,
    const float* __restrict__ rel, float* __restrict__ out,
    long long out_elems)
{
    __shared__ float2 qs[16 * 64];
    __shared__ float2 ks[16 * 64];
    __shared__ float2 vs[16 * 64];
    __shared__ float2 outh[16 * 64];

    const int b    = blockIdx.x;
    const int t    = threadIdx.x;
    const int lane = t & 63;
    const int wave = __builtin_amdgcn_readfirstlane(t >> 6);

    const float* xr = x_real + (size_t)b * 6144;
    const float* xi = x_imag + (size_t)b * 6144;

    float yr[12], yi[12];
#pragma unroll
    for (int j = 0; j < 12; ++j) { yr[j] = 0.f; yi[j] = 0.f; }

    const int g  = t >> 3;
    const int mo = t & 7;
    const int m0 = mo * 8;
    const int gi = g >> 3, gj = g & 7;

    for (int h = 0; h < HEADS; ++h) {
        {
            float ar[6], ai[6];
#pragma unroll
            for (int j = 0; j < 6; ++j) { ar[j] = 0.f; ai[j] = 0.f; }
            const int r0 = wave * 6;
            const float* wrp[6]; const float* wip[6];
#pragma unroll
            for (int j = 0; j < 6; ++j) {
                int r = r0 + j;
                int s = r >> 4;
                int o = s * 96 + h * 16 + (r & 15);
                wrp[j] = qkv_wr + o * 96;
                wip[j] = qkv_wi + o * 96;
            }
#pragma unroll 4
            for (int c = 0; c < 96; ++c) {
                float xre = xr[c * 64 + lane];
                float xim = xi[c * 64 + lane];
#pragma unroll
                for (int j = 0; j < 6; ++j) {
                    float wr = wrp[j][c], wi = wip[j][c];
                    ar[j] = fmaf(wr, xre, fmaf(-wi, xim, ar[j]));
                    ai[j] = fmaf(wr, xim, fmaf( wi, xre, ai[j]));
                }
            }
#pragma unroll
            for (int j = 0; j < 6; ++j) {
                int r  = r0 + j;
                int s  = r >> 4;
                int rd = r & 15;
                float scl   = (s == 0) ? SCALE : 1.0f;
                float2* dst = (s == 0) ? qs : ((s == 1) ? ks : vs);
                dst[rd * 64 + lane] = make_float2(ar[j] * scl, ai[j] * scl);
            }
        }
        __syncthreads();
        {
            float sr[8], si[8];
#pragma unroll
            for (int j = 0; j < 8; ++j) { sr[j] = 0.f; si[j] = 0.f; }
            for (int d = 0; d < 16; ++d) {
                float2 q2 = qs[d * 64 + g];
#pragma unroll
                for (int j = 0; j < 8; ++j) {
                    float2 k2 = ks[d * 64 + m0 + j];
                    sr[j] = fmaf(q2.x, k2.x, fmaf( q2.y, k2.y, sr[j]));
                    si[j] = fmaf(q2.y, k2.x, fmaf(-q2.x, k2.y, si[j]));
                }
            }
            const float* relh = rel + h * 225;
            float mag[8], e[8];
            float mx = -1e30f;
#pragma unroll
            for (int j = 0; j < 8; ++j) {
                int m = m0 + j;
                int idx = (gi - (m >> 3) + 7) * 15 + (gj - (m & 7) + 7);
                sr[j] += relh[idx];
                mag[j] = sqrtf(fmaf(sr[j], sr[j], si[j] * si[j]));
                mx = fmaxf(mx, mag[j]);
            }
            mx = fmaxf(mx, __shfl_xor(mx, 1));
            mx = fmaxf(mx, __shfl_xor(mx, 2));
            mx = fmaxf(mx, __shfl_xor(mx, 4));
            float ssum = 0.f;
#pragma unroll
            for (int j = 0; j < 8; ++j) { e[j] = __expf(mag[j] - mx); ssum += e[j]; }
            ssum += __shfl_xor(ssum, 1);
            ssum += __shfl_xor(ssum, 2);
            ssum += __shfl_xor(ssum, 4);
            float isum = 1.0f / ssum;
#pragma unroll
            for (int j = 0; j < 8; ++j) {
                float f = e[j] * isum / (mag[j] + 1e-8f);
                sr[j] *= f; si[j] *= f;
            }
            for (int d = 0; d < 16; ++d) {
                float pr = 0.f, pi = 0.f;
#pragma unroll
                for (int j = 0; j < 8; ++j) {
                    float2 v2 = vs[d * 64 + m0 + j];
                    pr = fmaf(sr[j], v2.x, fmaf(-si[j], v2.y, pr));
                    pi = fmaf(sr[j], v2.y, fmaf( si[j], v2.x, pi));
                }
                pr += __shfl_xor(pr, 1); pr += __shfl_xor(pr, 2); pr += __shfl_xor(pr, 4);
                pi += __shfl_xor(pi, 1); pi += __shfl_xor(pi, 2); pi += __shfl_xor(pi, 4);
                if (mo == 0) outh[d * 64 + g] = make_float2(pr, pi);
            }
        }
        __syncthreads();
        {
            const float* pr0 = proj_wr + (wave * 12) * 96 + h * 16;
            const float* pi0 = proj_wi + (wave * 12) * 96 + h * 16;
            for (int d = 0; d < 16; ++d) {
                float2 o2 = outh[d * 64 + lane];
#pragma unroll
                for (int j = 0; j < 12; ++j) {
                    float wr = pr0[j * 96 + d];
                    float wi = pi0[j * 96 + d];
                    yr[j] = fmaf(wr, o2.x, fmaf(-wi, o2.y, yr[j]));
                    yi[j] = fmaf(wr, o2.y, fmaf( wi, o2.x, yi[j]));
                }
            }
        }
        __syncthreads();
    }

    const long long n_total = (long long)gridDim.x * 6144;
#pragma unroll
    for (int j = 0; j < 12; ++j) {
        int o = wave * 12 + j;
        long long ci = (long long)b * 6144 + o * 64 + lane;
        if (ci < out_elems)           out[ci]           = yr[j];
        if (n_total + ci < out_elems) out[n_total + ci] = yi[j];
    }
}

// ===================== host =====================
extern "C" void kernel_launch(void* const* d_in, const int* in_sizes, int n_in,
                              void* d_out, int out_size, void* d_ws, size_t ws_size,
                              hipStream_t stream) {
    const float* x_real  = (const float*)d_in[0];
    const float* x_imag  = (const float*)d_in[1];
    const float* qkv_wr  = (const float*)d_in[2];
    const float* qkv_wi  = (const float*)d_in[3];
    const float* proj_wr = (const float*)d_in[4];
    const float* proj_wi = (const float*)d_in[5];
    const float* rel     = (const float*)d_in[6];
    float* out = (float*)d_out;

    const int B = in_sizes[0] / 6144;

    if (ws_size >= (size_t)WS_NEED) {
        __half* wq      = (__half*)d_ws;
        __half* wpq     = (__half*)((char*)d_ws + WS_WP_OFF);
        float*  rel_exp = (float*)((char*)d_ws + WS_REL_OFF);
        prep_kernel<<<(WQ_ELEMS + 255) / 256, 256, 0, stream>>>(
            qkv_wr, qkv_wi, proj_wr, proj_wi, rel, wq, wpq, rel_exp);
        fused_kernel<<<B, BLOCK, 0, stream>>>(
            x_real, x_imag, wq, wpq, rel_exp, out);
    } else {
        cwattn_kernel<<<B, BLOCK, 0, stream>>>(
            x_real, x_imag, qkv_wr, qkv_wi, proj_wr, proj_wi, rel, out,
            (long long)out_size);
    }
}

// Round 5
// 301.250 us; speedup vs baseline: 1.5558x; 1.5558x over previous
//
#include <hip/hip_runtime.h>
#include <hip/hip_fp16.h>

// ComplexWindowAttn: B=2048 windows, DIM=96, HEADS=6, HEAD_DIM=16, N=64 (8x8).
// R12: R11 structure (no xtr staging, direct global qkv B-frags, LDS 39.9 KB)
//      with the spill-inducing min-waves launch bound REMOVED.
//   R11 post-mortem: __launch_bounds__(512,6) forced VGPR 104->40; compiler
//   spilled all per-thread state (WRITE_SIZE 49->622 MB, FETCH +463 MB) and
//   the kernel went scratch-BW-bound. Natural footprint ~104-120 VGPR ->
//   4 waves/SIMD (2 blocks/CU), zero spill. Occupancy same as R10 but
//   without R10's xtr phase/barrier.
//   - scores: stored mg16 (R10-verified pack path, no triple recompute).
//   - scores/softmax/bpermute-PV/proj phases: R10-verified code verbatim.
// Fallback: verified R6 fused scalar kernel if ws too small.

#define HEADS 6
#define BLOCK 512
#define SCALE 0.25f

typedef _Float16 f16x8 __attribute__((ext_vector_type(8)));
typedef float    f32x4 __attribute__((ext_vector_type(4)));

#define WQ_ELEMS   27648              // 288*96 per plane
#define WS_WQ_B    165888             // 3 planes * 27648 * 2B
#define WS_WP_B    36864              // 96*192 f16
#define WS_REL_B   98304              // 6*64*64 f32
#define WS_WP_OFF  WS_WQ_B
#define WS_REL_OFF (WS_WQ_B + WS_WP_B)
#define WS_NEED    (WS_WQ_B + WS_WP_B + WS_REL_B)

// ===================== K1: weight/bias preparation =====================
__global__ void prep_kernel(const float* __restrict__ wr,
                            const float* __restrict__ wi,
                            const float* __restrict__ pwr,
                            const float* __restrict__ pwi,
                            const float* __restrict__ rel,
                            __half* __restrict__ wq,
                            __half* __restrict__ wp,
                            float* __restrict__ rel_exp)
{
    int i = blockIdx.x * 256 + threadIdx.x;
    if (i < WQ_ELEMS) {
        wq[i]                 = __float2half(wr[i]);
        wq[WQ_ELEMS + i]      = __float2half(wi[i]);
        wq[2 * WQ_ELEMS + i]  = __float2half(-wi[i]);
    }
    if (i < 9216) {                       // 96*96 proj weights -> packed
        int o = i / 96, c = i - o * 96;
        int h = c >> 4, d = c & 15;
        wp[o * 192 + h * 32 + d]      = __float2half(pwr[i]);
        wp[o * 192 + h * 32 + 16 + d] = __float2half(-pwi[i]);
    }
    if (i < 24576) {                      // rel -> TRANSPOSED [h][m][n]
        int h = i >> 12, m = (i >> 6) & 63, n = i & 63;
        int idx = ((n >> 3) - (m >> 3) + 7) * 15 + ((n & 7) - (m & 7) + 7);
        rel_exp[i] = rel[h * 225 + idx];
    }
}

// ===================== fused kernel =====================
// LDS map (f16 units), total 19968 f16 = 39936 B:
//   sQ  [2][64][40] @ 0      (5120)   per-round, re@d im@16+d, *SCALE
//   sK  [2][64][40] @ 5120   (5120)
//   sVr [2][16][72] @ 10240  (2304)   [d][m]
//   sVi [2][16][72] @ 12544  (2304)
//   sO  [2][64][40] @ 14848  (5120)   Or@d, Oi@16+d
__global__ __launch_bounds__(BLOCK) void fused_kernel(
    const float* __restrict__ x_real, const float* __restrict__ x_imag,
    const __half* __restrict__ wq,
    const __half* __restrict__ wp,
    const float* __restrict__ relT,
    float* __restrict__ out)
{
    __shared__ __align__(16) _Float16 smem[19968];

    _Float16* const sQ    = smem;
    _Float16* const sK    = smem + 5120;
    _Float16* const sVr   = smem + 10240;
    _Float16* const sVi   = smem + 12544;
    _Float16* const sO    = smem + 14848;

    const int b    = blockIdx.x;
    const int t    = threadIdx.x;
    const int lane = t & 63;
    const int w    = __builtin_amdgcn_readfirstlane(t >> 6);
    const int l16  = lane & 15;
    const int quad = lane >> 4;

    const float* xr = x_real + (size_t)b * 6144;   // [c][n]
    const float* xi = x_imag + (size_t)b * 6144;

    f32x4 pacc0 = {0.f,0.f,0.f,0.f};
    f32x4 pacc1 = {0.f,0.f,0.f,0.f};
    f32x4 pacc2 = {0.f,0.f,0.f,0.f};

    const _Float16* wpf = reinterpret_cast<const _Float16*>(wp);
    const __half* wr_p  = wq;
    const __half* wi_p  = wq + WQ_ELEMS;
    const __half* wni_p = wq + 2 * WQ_ELEMS;

    const int hr = w >> 2;          // head-in-round for attn (0/1)
    const int nb = w & 3;           // 16-col n-block for attn

    for (int ro = 0; ro < 3; ++ro) {
        // ---------- qkv cGEMM for heads 2ro, 2ro+1 ----------
        {
            // B-frags for this wave's tile (nt = w&3), loaded once from global
            const int n0 = (w & 3) * 16;
            f16x8 b_r[3], b_i[3];
#pragma unroll
            for (int ks = 0; ks < 3; ++ks) {
                const float* xrp = xr + (ks * 32 + quad * 8) * 64 + n0 + l16;
                const float* xip = xi + (ks * 32 + quad * 8) * 64 + n0 + l16;
                f16x8 vr, vi;
#pragma unroll
                for (int j = 0; j < 8; ++j) {
                    vr[j] = (_Float16)xrp[j * 64];
                    vi[j] = (_Float16)xip[j * 64];
                }
                b_r[ks] = vr;
                b_i[ks] = vi;
            }
#pragma unroll
            for (int ui = 0; ui < 3; ++ui) {
                const int ml  = (w >> 2) * 3 + ui;   // 0..5
                const int hl  = ml & 1;              // head-local
                const int mat = ml >> 1;             // 0=Q,1=K,2=V
                const int tile = mat * 6 + ro * 2 + hl;
                f16x8 a_r[3], a_i[3], a_ni[3];
#pragma unroll
                for (int ks = 0; ks < 3; ++ks) {
                    size_t off = (size_t)(tile * 16 + l16) * 96 + ks * 32 + quad * 8;
                    a_r[ks]  = *reinterpret_cast<const f16x8*>(wr_p  + off);
                    a_i[ks]  = *reinterpret_cast<const f16x8*>(wi_p  + off);
                    a_ni[ks] = *reinterpret_cast<const f16x8*>(wni_p + off);
                }
                f32x4 accr = {0.f, 0.f, 0.f, 0.f};
                f32x4 acci = {0.f, 0.f, 0.f, 0.f};
#pragma unroll
                for (int ks = 0; ks < 3; ++ks) {
                    accr = __builtin_amdgcn_mfma_f32_16x16x32_f16(a_r[ks],  b_r[ks], accr, 0, 0, 0);
                    accr = __builtin_amdgcn_mfma_f32_16x16x32_f16(a_ni[ks], b_i[ks], accr, 0, 0, 0);
                    acci = __builtin_amdgcn_mfma_f32_16x16x32_f16(a_r[ks],  b_i[ks], acci, 0, 0, 0);
                    acci = __builtin_amdgcn_mfma_f32_16x16x32_f16(a_i[ks],  b_r[ks], acci, 0, 0, 0);
                }
                // C: col n = n0+l16, row d = quad*4 + r (verified layout)
                const int n = n0 + l16;
                if (mat == 0) {                 // Q, pre-scaled
                    _Float16* q = sQ + hl * 2560 + n * 40;
#pragma unroll
                    for (int r = 0; r < 4; ++r) {
                        q[quad * 4 + r]      = (_Float16)(accr[r] * SCALE);
                        q[16 + quad * 4 + r] = (_Float16)(acci[r] * SCALE);
                    }
                } else if (mat == 1) {          // K
                    _Float16* kk = sK + hl * 2560 + n * 40;
#pragma unroll
                    for (int r = 0; r < 4; ++r) {
                        kk[quad * 4 + r]      = (_Float16)accr[r];
                        kk[16 + quad * 4 + r] = (_Float16)acci[r];
                    }
                } else {                        // V -> [d][m]
#pragma unroll
                    for (int r = 0; r < 4; ++r) {
                        sVr[hl * 1152 + (quad * 4 + r) * 72 + n] = (_Float16)accr[r];
                        sVi[hl * 1152 + (quad * 4 + r) * 72 + n] = (_Float16)acci[r];
                    }
                }
            }
        }
        __syncthreads();                        // B1

        const int hl = hr;
        const int hh = ro * 2 + hr;

        // ---------- swapped scores: C[m][n], lane owns n = nb*16+l16 ----------
        float sr16[4][4], si16[4][4], mg16[4][4];
        float mx = -1e30f;
        {
            const _Float16* qrow = sQ + hl * 2560 + (nb * 16 + l16) * 40;
            f16x8 bq  = *reinterpret_cast<const f16x8*>(qrow + quad * 8);
            f16x8 bq2 = *reinterpret_cast<const f16x8*>(qrow + ((quad + 2) & 3) * 8);
            if (quad >= 2) bq2 = -bq2;          // [Qi | -Qr]
#pragma unroll
            for (int tm = 0; tm < 4; ++tm) {
                f16x8 ak = *reinterpret_cast<const f16x8*>(
                    sK + hl * 2560 + (tm * 16 + l16) * 40 + quad * 8);
                f32x4 fr = {0.f,0.f,0.f,0.f}, fi = {0.f,0.f,0.f,0.f};
                fr = __builtin_amdgcn_mfma_f32_16x16x32_f16(ak, bq,  fr, 0, 0, 0);
                fi = __builtin_amdgcn_mfma_f32_16x16x32_f16(ak, bq2, fi, 0, 0, 0);
#pragma unroll
                for (int r = 0; r < 4; ++r) {
                    const int m = tm * 16 + quad * 4 + r;
                    float bb  = relT[hh * 4096 + m * 64 + nb * 16 + l16];
                    float vr_ = fr[r] + bb;
                    float vi_ = fi[r];
                    sr16[tm][r] = vr_; si16[tm][r] = vi_;
                    float m2  = fmaf(vr_, vr_, vi_ * vi_);
                    float rs  = __frsqrt_rn(m2 + 1e-16f);
                    float mag = m2 * rs;        // == sqrt(m2), 0 at m2=0
                    mg16[tm][r] = mag;
                    mx = fmaxf(mx, mag);
                }
            }
        }
        mx = fmaxf(mx, __shfl_xor(mx, 16));
        mx = fmaxf(mx, __shfl_xor(mx, 32));
        float ss = 0.f;
#pragma unroll
        for (int tm = 0; tm < 4; ++tm)
#pragma unroll
            for (int r = 0; r < 4; ++r)
                ss += __expf(mg16[tm][r] - mx);
        ss += __shfl_xor(ss, 16);
        ss += __shfl_xor(ss, 32);
        const float inv = 1.0f / ss;

        // ---------- pack P[tm] (4 f16 per plane) ----------
        uint2 Pr[4], Pi[4];
#pragma unroll
        for (int tm = 0; tm < 4; ++tm) {
            float f_[4];
#pragma unroll
            for (int r = 0; r < 4; ++r) {
                float mag = mg16[tm][r];
                float rs  = __frsqrt_rn(fmaf(mag, mag, 1e-16f));
                f_[r] = __expf(mag - mx) * inv * rs;
            }
            __half2 r01 = __floats2half2_rn(sr16[tm][0]*f_[0], sr16[tm][1]*f_[1]);
            __half2 r23 = __floats2half2_rn(sr16[tm][2]*f_[2], sr16[tm][3]*f_[3]);
            __half2 i01 = __floats2half2_rn(si16[tm][0]*f_[0], si16[tm][1]*f_[1]);
            __half2 i23 = __floats2half2_rn(si16[tm][2]*f_[2], si16[tm][3]*f_[3]);
            Pr[tm].x = *reinterpret_cast<unsigned*>(&r01);
            Pr[tm].y = *reinterpret_cast<unsigned*>(&r23);
            Pi[tm].x = *reinterpret_cast<unsigned*>(&i01);
            Pi[tm].y = *reinterpret_cast<unsigned*>(&i23);
        }

        // ---------- exchange -> PV A-frags, then PV MFMA ----------
        {
            const int srcA = (l16 + ((quad & 1) << 5)) << 2;
            const int srcB = srcA + 64;
            const bool hiq = (quad >= 2);
            union FU { unsigned u[4]; f16x8 v; };
            f32x4 oar = {0.f,0.f,0.f,0.f}, oai = {0.f,0.f,0.f,0.f};
#pragma unroll
            for (int ks = 0; ks < 2; ++ks) {
                FU fr_, fi_;
                {
                    unsigned a0 = __builtin_amdgcn_ds_bpermute(srcA, (int)Pr[2*ks].x);
                    unsigned a1 = __builtin_amdgcn_ds_bpermute(srcA, (int)Pr[2*ks].y);
                    unsigned a2 = __builtin_amdgcn_ds_bpermute(srcA, (int)Pr[2*ks+1].x);
                    unsigned a3 = __builtin_amdgcn_ds_bpermute(srcA, (int)Pr[2*ks+1].y);
                    unsigned b0 = __builtin_amdgcn_ds_bpermute(srcB, (int)Pr[2*ks].x);
                    unsigned b1 = __builtin_amdgcn_ds_bpermute(srcB, (int)Pr[2*ks].y);
                    unsigned b2 = __builtin_amdgcn_ds_bpermute(srcB, (int)Pr[2*ks+1].x);
                    unsigned b3 = __builtin_amdgcn_ds_bpermute(srcB, (int)Pr[2*ks+1].y);
                    fr_.u[0] = hiq ? a2 : a0;  fr_.u[1] = hiq ? a3 : a1;
                    fr_.u[2] = hiq ? b2 : b0;  fr_.u[3] = hiq ? b3 : b1;
                }
                {
                    unsigned a0 = __builtin_amdgcn_ds_bpermute(srcA, (int)Pi[2*ks].x);
                    unsigned a1 = __builtin_amdgcn_ds_bpermute(srcA, (int)Pi[2*ks].y);
                    unsigned a2 = __builtin_amdgcn_ds_bpermute(srcA, (int)Pi[2*ks+1].x);
                    unsigned a3 = __builtin_amdgcn_ds_bpermute(srcA, (int)Pi[2*ks+1].y);
                    unsigned b0 = __builtin_amdgcn_ds_bpermute(srcB, (int)Pi[2*ks].x);
                    unsigned b1 = __builtin_amdgcn_ds_bpermute(srcB, (int)Pi[2*ks].y);
                    unsigned b2 = __builtin_amdgcn_ds_bpermute(srcB, (int)Pi[2*ks+1].x);
                    unsigned b3 = __builtin_amdgcn_ds_bpermute(srcB, (int)Pi[2*ks+1].y);
                    fi_.u[0] = hiq ? a2 : a0;  fi_.u[1] = hiq ? a3 : a1;
                    fi_.u[2] = hiq ? b2 : b0;  fi_.u[3] = hiq ? b3 : b1;
                }
                const int ko = ks * 32 + quad * 8;
                f16x8 vr_ = *reinterpret_cast<const f16x8*>(&sVr[hl * 1152 + l16 * 72 + ko]);
                f16x8 vi_ = *reinterpret_cast<const f16x8*>(&sVi[hl * 1152 + l16 * 72 + ko]);
                oar = __builtin_amdgcn_mfma_f32_16x16x32_f16(fr_.v,  vr_,  oar, 0, 0, 0);
                oar = __builtin_amdgcn_mfma_f32_16x16x32_f16(fi_.v, -vi_,  oar, 0, 0, 0);
                oai = __builtin_amdgcn_mfma_f32_16x16x32_f16(fr_.v,  vi_,  oai, 0, 0, 0);
                oai = __builtin_amdgcn_mfma_f32_16x16x32_f16(fi_.v,  vr_,  oai, 0, 0, 0);
            }
#pragma unroll
            for (int r = 0; r < 4; ++r) {
                const int n = nb * 16 + quad * 4 + r;
                sO[hl * 2560 + n * 40 + l16]      = (_Float16)oar[r];
                sO[hl * 2560 + n * 40 + 16 + l16] = (_Float16)oai[r];
            }
        }
        __syncthreads();                        // B2

        // ---------- proj accumulate (R9-verified math) ----------
        {
            const int ob0 = (w & 1) * 3;
            const int pnb = w >> 1;
#pragma unroll
            for (int h2 = 0; h2 < 2; ++h2) {
                const _Float16* wb = wpf + (ro * 2 + h2) * 32 + quad * 8;
                f16x8 wb0 = *reinterpret_cast<const f16x8*>(wb + ((ob0    ) * 16 + l16) * 192);
                f16x8 wb1 = *reinterpret_cast<const f16x8*>(wb + ((ob0 + 1) * 16 + l16) * 192);
                f16x8 wb2 = *reinterpret_cast<const f16x8*>(wb + ((ob0 + 2) * 16 + l16) * 192);
                f16x8 a = *reinterpret_cast<const f16x8*>(
                    &sO[h2 * 2560 + (pnb * 16 + l16) * 40 + quad * 8]);
                pacc0 = __builtin_amdgcn_mfma_f32_16x16x32_f16(a, wb0, pacc0, 0, 0, 0);
                pacc1 = __builtin_amdgcn_mfma_f32_16x16x32_f16(a, wb1, pacc1, 0, 0, 0);
                pacc2 = __builtin_amdgcn_mfma_f32_16x16x32_f16(a, wb2, pacc2, 0, 0, 0);
            }
        }
        // next round's qkv writes (sQ/sK/sV) are disjoint from sO reads here;
        // B1 of the next round orders proj reads before the next sO writes.
    }

    // ---------- epilogue: out[o][n], o = (w&1)*48 + j*16 + l16 ----------
    {
        float* op = out + (size_t)b * 6144 + ((w & 1) * 48 + l16) * 64
                  + (w >> 1) * 16 + quad * 4;
        *reinterpret_cast<f32x4*>(op)        = pacc0;
        *reinterpret_cast<f32x4*>(op + 1024) = pacc1;
        *reinterpret_cast<f32x4*>(op + 2048) = pacc2;
    }
}

// ===================== Fallback: verified R6 fused kernel =====================
__global__ __launch_bounds__(BLOCK) void cwattn_kernel(
    const float* __restrict__ x_real, const float* __restrict__ x_imag,
    const float* __restrict__ qkv_wr, const float* __restrict__ qkv_wi,
    const float* __restrict__ proj_wr, const float* __restrict__ proj_wi,
    const float* __restrict__ rel, float* __restrict__ out,
    long long out_elems)
{
    __shared__ float2 qs[16 * 64];
    __shared__ float2 ks[16 * 64];
    __shared__ float2 vs[16 * 64];
    __shared__ float2 outh[16 * 64];

    const int b    = blockIdx.x;
    const int t    = threadIdx.x;
    const int lane = t & 63;
    const int wave = __builtin_amdgcn_readfirstlane(t >> 6);

    const float* xr = x_real + (size_t)b * 6144;
    const float* xi = x_imag + (size_t)b * 6144;

    float yr[12], yi[12];
#pragma unroll
    for (int j = 0; j < 12; ++j) { yr[j] = 0.f; yi[j] = 0.f; }

    const int g  = t >> 3;
    const int mo = t & 7;
    const int m0 = mo * 8;
    const int gi = g >> 3, gj = g & 7;

    for (int h = 0; h < HEADS; ++h) {
        {
            float ar[6], ai[6];
#pragma unroll
            for (int j = 0; j < 6; ++j) { ar[j] = 0.f; ai[j] = 0.f; }
            const int r0 = wave * 6;
            const float* wrp[6]; const float* wip[6];
#pragma unroll
            for (int j = 0; j < 6; ++j) {
                int r = r0 + j;
                int s = r >> 4;
                int o = s * 96 + h * 16 + (r & 15);
                wrp[j] = qkv_wr + o * 96;
                wip[j] = qkv_wi + o * 96;
            }
#pragma unroll 4
            for (int c = 0; c < 96; ++c) {
                float xre = xr[c * 64 + lane];
                float xim = xi[c * 64 + lane];
#pragma unroll
                for (int j = 0; j < 6; ++j) {
                    float wr = wrp[j][c], wi = wip[j][c];
                    ar[j] = fmaf(wr, xre, fmaf(-wi, xim, ar[j]));
                    ai[j] = fmaf(wr, xim, fmaf( wi, xre, ai[j]));
                }
            }
#pragma unroll
            for (int j = 0; j < 6; ++j) {
                int r  = r0 + j;
                int s  = r >> 4;
                int rd = r & 15;
                float scl   = (s == 0) ? SCALE : 1.0f;
                float2* dst = (s == 0) ? qs : ((s == 1) ? ks : vs);
                dst[rd * 64 + lane] = make_float2(ar[j] * scl, ai[j] * scl);
            }
        }
        __syncthreads();
        {
            float sr[8], si[8];
#pragma unroll
            for (int j = 0; j < 8; ++j) { sr[j] = 0.f; si[j] = 0.f; }
            for (int d = 0; d < 16; ++d) {
                float2 q2 = qs[d * 64 + g];
#pragma unroll
                for (int j = 0; j < 8; ++j) {
                    float2 k2 = ks[d * 64 + m0 + j];
                    sr[j] = fmaf(q2.x, k2.x, fmaf( q2.y, k2.y, sr[j]));
                    si[j] = fmaf(q2.y, k2.x, fmaf(-q2.x, k2.y, si[j]));
                }
            }
            const float* relh = rel + h * 225;
            float mag[8], e[8];
            float mx = -1e30f;
#pragma unroll
            for (int j = 0; j < 8; ++j) {
                int m = m0 + j;
                int idx = (gi - (m >> 3) + 7) * 15 + (gj - (m & 7) + 7);
                sr[j] += relh[idx];
                mag[j] = sqrtf(fmaf(sr[j], sr[j], si[j] * si[j]));
                mx = fmaxf(mx, mag[j]);
            }
            mx = fmaxf(mx, __shfl_xor(mx, 1));
            mx = fmaxf(mx, __shfl_xor(mx, 2));
            mx = fmaxf(mx, __shfl_xor(mx, 4));
            float ssum = 0.f;
#pragma unroll
            for (int j = 0; j < 8; ++j) { e[j] = __expf(mag[j] - mx); ssum += e[j]; }
            ssum += __shfl_xor(ssum, 1);
            ssum += __shfl_xor(ssum, 2);
            ssum += __shfl_xor(ssum, 4);
            float isum = 1.0f / ssum;
#pragma unroll
            for (int j = 0; j < 8; ++j) {
                float f = e[j] * isum / (mag[j] + 1e-8f);
                sr[j] *= f; si[j] *= f;
            }
            for (int d = 0; d < 16; ++d) {
                float pr = 0.f, pi = 0.f;
#pragma unroll
                for (int j = 0; j < 8; ++j) {
                    float2 v2 = vs[d * 64 + m0 + j];
                    pr = fmaf(sr[j], v2.x, fmaf(-si[j], v2.y, pr));
                    pi = fmaf(sr[j], v2.y, fmaf( si[j], v2.x, pi));
                }
                pr += __shfl_xor(pr, 1); pr += __shfl_xor(pr, 2); pr += __shfl_xor(pr, 4);
                pi += __shfl_xor(pi, 1); pi += __shfl_xor(pi, 2); pi += __shfl_xor(pi, 4);
                if (mo == 0) outh[d * 64 + g] = make_float2(pr, pi);
            }
        }
        __syncthreads();
        {
            const float* pr0 = proj_wr + (wave * 12) * 96 + h * 16;
            const float* pi0 = proj_wi + (wave * 12) * 96 + h * 16;
            for (int d = 0; d < 16; ++d) {
                float2 o2 = outh[d * 64 + lane];
#pragma unroll
                for (int j = 0; j < 12; ++j) {
                    float wr = pr0[j * 96 + d];
                    float wi = pi0[j * 96 + d];
                    yr[j] = fmaf(wr, o2.x, fmaf(-wi, o2.y, yr[j]));
                    yi[j] = fmaf(wr, o2.y, fmaf( wi, o2.x, yi[j]));
                }
            }
        }
        __syncthreads();
    }

    const long long n_total = (long long)gridDim.x * 6144;
#pragma unroll
    for (int j = 0; j < 12; ++j) {
        int o = wave * 12 + j;
        long long ci = (long long)b * 6144 + o * 64 + lane;
        if (ci < out_elems)           out[ci]           = yr[j];
        if (n_total + ci < out_elems) out[n_total + ci] = yi[j];
    }
}

// ===================== host =====================
extern "C" void kernel_launch(void* const* d_in, const int* in_sizes, int n_in,
                              void* d_out, int out_size, void* d_ws, size_t ws_size,
                              hipStream_t stream) {
    const float* x_real  = (const float*)d_in[0];
    const float* x_imag  = (const float*)d_in[1];
    const float* qkv_wr  = (const float*)d_in[2];
    const float* qkv_wi  = (const float*)d_in[3];
    const float* proj_wr = (const float*)d_in[4];
    const float* proj_wi = (const float*)d_in[5];
    const float* rel     = (const float*)d_in[6];
    float* out = (float*)d_out;

    const int B = in_sizes[0] / 6144;

    if (ws_size >= (size_t)WS_NEED) {
        __half* wq      = (__half*)d_ws;
        __half* wpq     = (__half*)((char*)d_ws + WS_WP_OFF);
        float*  rel_exp = (float*)((char*)d_ws + WS_REL_OFF);
        prep_kernel<<<(WQ_ELEMS + 255) / 256, 256, 0, stream>>>(
            qkv_wr, qkv_wi, proj_wr, proj_wi, rel, wq, wpq, rel_exp);
        fused_kernel<<<B, BLOCK, 0, stream>>>(
            x_real, x_imag, wq, wpq, rel_exp, out);
    } else {
        cwattn_kernel<<<B, BLOCK, 0, stream>>>(
            x_real, x_imag, qkv_wr, qkv_wi, proj_wr, proj_wi, rel, out,
            (long long)out_size);
    }
}